// Round 1
// baseline (415.522 us; speedup 1.0000x reference)
//
#include <hip/hip_runtime.h>
#include <stdint.h>

typedef unsigned short ushort_t;
typedef __attribute__((ext_vector_type(8))) short short8;
typedef __attribute__((ext_vector_type(4))) float floatx4;
typedef __attribute__((ext_vector_type(4))) float floatv4;
typedef __attribute__((ext_vector_type(4))) unsigned short ushortv4;

// Problem constants
// B=64, I=128, J=512, H=16, D=64, QD=512, KVD=256, HID=1024

__device__ __forceinline__ ushort_t f2bf(float x) {
    union { float f; unsigned u; } v; v.f = x;
    unsigned r = v.u + 0x7fffu + ((v.u >> 16) & 1u);   // RNE
    return (ushort_t)(r >> 16);
}
__device__ __forceinline__ float bf2f(ushort_t x) {
    union { unsigned u; float f; } v; v.u = ((unsigned)x) << 16; return v.f;
}

// ---------------- cast fp32 -> bf16 (vectorized) ----------------
__global__ void cast_bf16_kernel(const float* __restrict__ src,
                                 ushort_t* __restrict__ dst, int n4) {
    int t = blockIdx.x * 256 + threadIdx.x;
    if (t >= n4) return;
    floatv4 v = ((const floatv4*)src)[t];
    ushortv4 o;
    o[0] = f2bf(v[0]); o[1] = f2bf(v[1]); o[2] = f2bf(v[2]); o[3] = f2bf(v[3]);
    ((ushortv4*)dst)[t] = o;
}

// ---------------- transpose+cast: W (K x N fp32) -> Wt (N x K bf16), scaled --
__global__ void tcast_kernel(const float* __restrict__ src,
                             ushort_t* __restrict__ dst, int K, int N, float scale) {
    int t = blockIdx.x * 256 + threadIdx.x;
    if (t >= K * N) return;
    int n = t / K, k = t - n * K;
    dst[t] = f2bf(src[k * N + n] * scale);
}

// ---------------- GEMM: C = A (MxK) * Bt^T, A,Bt bf16 row-major, Bt is NxK ---
// 128x128 block tile, BK=64, 256 threads (4 waves in 2x2), 16x16x32 bf16 MFMA.
// emode 0: out_a = qattn (b,h,i,d) bf16 scatter          [M=8192,N=1024]
// emode 1: out_a = kbuf, out_b = vbuf, (b,h,j,d) bf16    [M=32768,N=2048]
// emode 2: out_f = fp32 row-major + bias[col]            [M=8192,N=512]
__global__ __launch_bounds__(256) void gemm_bt_kernel(
    const ushort_t* __restrict__ A, const ushort_t* __restrict__ Bt,
    int M, int N, int K, int emode,
    ushort_t* __restrict__ out_a, ushort_t* __restrict__ out_b,
    float* __restrict__ out_f, const float* __restrict__ bias)
{
    __shared__ ushort_t sA[128 * 64];
    __shared__ ushort_t sB[128 * 64];

    const int tid  = threadIdx.x;
    const int lane = tid & 63;
    const int w    = tid >> 6;
    const int quad = lane >> 4;
    const int l15  = lane & 15;
    const int wr   = w >> 1, wc = w & 1;
    const int m0 = blockIdx.y * 128;
    const int n0 = blockIdx.x * 128;

    floatx4 acc[4][4];
#pragma unroll
    for (int i = 0; i < 4; i++)
#pragma unroll
        for (int j = 0; j < 4; j++) acc[i][j] = (floatx4){0.f, 0.f, 0.f, 0.f};

    for (int k0 = 0; k0 < K; k0 += 64) {
        __syncthreads();
#pragma unroll
        for (int i = 0; i < 4; i++) {
            int c = tid + i * 256;          // 0..1023
            int row = c >> 3, col = (c & 7) * 8;
            *(short8*)&sA[row * 64 + col] =
                *(const short8*)&A[(m0 + row) * K + k0 + col];
            *(short8*)&sB[row * 64 + col] =
                *(const short8*)&Bt[(n0 + row) * K + k0 + col];
        }
        __syncthreads();
#pragma unroll
        for (int ks = 0; ks < 64; ks += 32) {
            short8 af[4], bf[4];
#pragma unroll
            for (int i = 0; i < 4; i++)
                af[i] = *(const short8*)&sA[(wr * 64 + i * 16 + l15) * 64 + ks + quad * 8];
#pragma unroll
            for (int j = 0; j < 4; j++)
                bf[j] = *(const short8*)&sB[(wc * 64 + j * 16 + l15) * 64 + ks + quad * 8];
#pragma unroll
            for (int i = 0; i < 4; i++)
#pragma unroll
                for (int j = 0; j < 4; j++)
                    acc[i][j] = __builtin_amdgcn_mfma_f32_16x16x32_bf16(
                        af[i], bf[j], acc[i][j], 0, 0, 0);
        }
    }

    // epilogue: C row = quad*4+reg, col = lane&15 (verified m89/m91 layout)
#pragma unroll
    for (int i = 0; i < 4; i++) {
#pragma unroll
        for (int j = 0; j < 4; j++) {
#pragma unroll
            for (int r = 0; r < 4; r++) {
                int grow = m0 + wr * 64 + i * 16 + quad * 4 + r;
                int gcol = n0 + wc * 64 + j * 16 + l15;
                float v = acc[i][j][r];
                if (emode == 0) {
                    int b = grow >> 7, ii = grow & 127;
                    int h = gcol >> 6, d = gcol & 63;
                    out_a[((b * 16 + h) * 128 + ii) * 64 + d] = f2bf(v);
                } else if (emode == 1) {
                    int b = grow >> 9, jj = grow & 511;
                    int c = gcol & 1023, h = c >> 6, d = c & 63;
                    ushort_t* dst = (gcol < 1024) ? out_a : out_b;
                    dst[((b * 16 + h) * 512 + jj) * 64 + d] = f2bf(v);
                } else {
                    out_f[grow * N + gcol] = v + bias[gcol];
                }
            }
        }
    }
}

// ---------------- fused attention ----------------
// grid = B*H = 1024 blocks, 512 threads (8 waves).
// LDS: K tile (512x64 bf16, 64KB) + V^T tile (64x512 bf16, 64KB) + S (16x512 bf16, 16KB)
// Per i-chunk of 16 rows: S = Q*K^T (scale folded into Wq), softmax in-place, O = P*V.
__global__ __launch_bounds__(512) void attn_kernel(
    const ushort_t* __restrict__ Q,    // (B*H, 128, 64)
    const ushort_t* __restrict__ Kb,   // (B*H, 512, 64)
    const ushort_t* __restrict__ Vb,   // (B*H, 512, 64)
    ushort_t* __restrict__ O)          // (B*128, 1024) = (b,i,h*64+d)
{
    __shared__ ushort_t sK[512 * 64];
    __shared__ ushort_t sVt[64 * 512];
    __shared__ ushort_t sS[16 * 512];

    const int bh = blockIdx.x;
    const int b = bh >> 4, h = bh & 15;
    const int tid  = threadIdx.x;
    const int lane = tid & 63, w = tid >> 6;
    const int quad = lane >> 4, l15 = lane & 15;

    const ushort_t* kg = Kb + bh * 32768;
    const ushort_t* vg = Vb + bh * 32768;
    const ushort_t* qg = Q  + bh * 8192;

    // stage K (straight copy) and V (transposed) into LDS
#pragma unroll
    for (int i = 0; i < 8; i++) {
        int c = tid + i * 512;              // 0..4095 chunks of 8 ushorts
        *(short8*)&sK[c * 8] = *(const short8*)&kg[c * 8];
    }
#pragma unroll
    for (int i = 0; i < 8; i++) {
        int c = tid + i * 512;
        int j = c >> 3, d0 = (c & 7) * 8;
        short8 v = *(const short8*)&vg[c * 8];
#pragma unroll
        for (int e = 0; e < 8; e++) sVt[(d0 + e) * 512 + j] = (ushort_t)v[e];
    }
    __syncthreads();

    for (int ic = 0; ic < 8; ic++) {
        const int i0 = ic * 16;
        // Q fragments for this chunk (A-layout: m=lane&15, k=quad*8+j)
        short8 aq0 = *(const short8*)&qg[(i0 + l15) * 64 + quad * 8];
        short8 aq1 = *(const short8*)&qg[(i0 + l15) * 64 + 32 + quad * 8];

        // ---- S = Q * K^T : 32 j-tiles, 4 per wave ----
#pragma unroll
        for (int jj = 0; jj < 4; jj++) {
            int jt = w * 4 + jj;
            floatx4 acc = (floatx4){0.f, 0.f, 0.f, 0.f};
            short8 bk0 = *(const short8*)&sK[(jt * 16 + l15) * 64 + quad * 8];
            short8 bk1 = *(const short8*)&sK[(jt * 16 + l15) * 64 + 32 + quad * 8];
            acc = __builtin_amdgcn_mfma_f32_16x16x32_bf16(aq0, bk0, acc, 0, 0, 0);
            acc = __builtin_amdgcn_mfma_f32_16x16x32_bf16(aq1, bk1, acc, 0, 0, 0);
#pragma unroll
            for (int r = 0; r < 4; r++)
                sS[(quad * 4 + r) * 512 + jt * 16 + l15] = f2bf(acc[r]);
        }
        __syncthreads();

        // ---- softmax: 16 rows, 32 threads/row, 16 elems/thread ----
        {
            int row = tid >> 5, g = tid & 31;
            ushort_t* sp = &sS[row * 512 + g * 16];
            short8 r0 = *(const short8*)sp;
            short8 r1 = *(const short8*)(sp + 8);
            float vals[16];
#pragma unroll
            for (int e = 0; e < 8; e++) {
                vals[e]     = bf2f((ushort_t)r0[e]);
                vals[8 + e] = bf2f((ushort_t)r1[e]);
            }
            float m = -1e30f;
#pragma unroll
            for (int e = 0; e < 16; e++) m = fmaxf(m, vals[e]);
#pragma unroll
            for (int off = 16; off > 0; off >>= 1) m = fmaxf(m, __shfl_xor(m, off));
            float s = 0.f;
#pragma unroll
            for (int e = 0; e < 16; e++) { vals[e] = __expf(vals[e] - m); s += vals[e]; }
#pragma unroll
            for (int off = 16; off > 0; off >>= 1) s += __shfl_xor(s, off);
            float inv = 1.0f / s;
            short8 o0, o1;
#pragma unroll
            for (int e = 0; e < 8; e++) {
                o0[e] = (short)f2bf(vals[e] * inv);
                o1[e] = (short)f2bf(vals[8 + e] * inv);
            }
            *(short8*)sp       = o0;
            *(short8*)(sp + 8) = o1;
        }
        __syncthreads();

        // ---- O = P * V : waves 0..3, one 16x16 d-tile each, K=512 ----
        if (w < 4) {
            floatx4 acc = (floatx4){0.f, 0.f, 0.f, 0.f};
#pragma unroll
            for (int kk = 0; kk < 16; kk++) {
                short8 ap = *(const short8*)&sS[l15 * 512 + kk * 32 + quad * 8];
                short8 bv = *(const short8*)&sVt[(w * 16 + l15) * 512 + kk * 32 + quad * 8];
                acc = __builtin_amdgcn_mfma_f32_16x16x32_bf16(ap, bv, acc, 0, 0, 0);
            }
#pragma unroll
            for (int r = 0; r < 4; r++) {
                int gi = b * 128 + i0 + quad * 4 + r;
                O[gi * 1024 + h * 64 + w * 16 + l15] = f2bf(acc[r]);
            }
        }
        __syncthreads();
    }
}

// ---------------- launch ----------------
extern "C" void kernel_launch(void* const* d_in, const int* in_sizes, int n_in,
                              void* d_out, int out_size, void* d_ws, size_t ws_size,
                              hipStream_t stream) {
    const float* q   = (const float*)d_in[0];   // (64,128,512)
    const float* kv  = (const float*)d_in[1];   // (64,512,256)
    const float* Wq  = (const float*)d_in[2];   // (512,1024)
    const float* Wkv = (const float*)d_in[3];   // (256,2048)
    const float* Wo  = (const float*)d_in[4];   // (1024,512)
    const float* bo  = (const float*)d_in[5];   // (512,)
    float* out = (float*)d_out;

    char* ws = (char*)d_ws;
    ushort_t* qA    = (ushort_t*)(ws + 0);          //  8 MB  (8192 x 512)
    ushort_t* kvA   = (ushort_t*)(ws + 8388608);    // 16 MB  (32768 x 256)
    ushort_t* WqT   = (ushort_t*)(ws + 25165824);   //  1 MB  (1024 x 512)
    ushort_t* WkvT  = (ushort_t*)(ws + 26214400);   //  1 MB  (2048 x 256)
    ushort_t* WoT   = (ushort_t*)(ws + 27262976);   //  1 MB  (512 x 1024)
    ushort_t* qattn = (ushort_t*)(ws + 28311552);   // 16 MB  (b,h,i,d)
    ushort_t* kbuf  = (ushort_t*)(ws + 45088768);   // 64 MB  (b,h,j,d)
    ushort_t* vbuf  = (ushort_t*)(ws + 112197632);  // 64 MB  (b,h,j,d)
    ushort_t* attnO = (ushort_t*)(ws + 179306496);  // 16 MB  (b,i,h*64+d)

    const float scale = 0.125f;  // HEAD_DIM^-0.5, folded into Wq

    hipLaunchKernelGGL(cast_bf16_kernel, dim3(4096), dim3(256), 0, stream, q,  qA,  4194304 / 4);
    hipLaunchKernelGGL(cast_bf16_kernel, dim3(8192), dim3(256), 0, stream, kv, kvA, 8388608 / 4);
    hipLaunchKernelGGL(tcast_kernel, dim3(2048), dim3(256), 0, stream, Wq,  WqT,  512,  1024, scale);
    hipLaunchKernelGGL(tcast_kernel, dim3(2048), dim3(256), 0, stream, Wkv, WkvT, 256,  2048, 1.0f);
    hipLaunchKernelGGL(tcast_kernel, dim3(2048), dim3(256), 0, stream, Wo,  WoT,  1024, 512,  1.0f);

    // query = q @ Wq  (scaled), scattered to (b,h,i,d)
    hipLaunchKernelGGL(gemm_bt_kernel, dim3(8, 64), dim3(256), 0, stream,
                       qA, WqT, 8192, 1024, 512, 0, qattn, (ushort_t*)nullptr,
                       (float*)nullptr, (const float*)nullptr);
    // k,v = kv @ Wkv, scattered to (b,h,j,d)
    hipLaunchKernelGGL(gemm_bt_kernel, dim3(16, 256), dim3(256), 0, stream,
                       kvA, WkvT, 32768, 2048, 256, 1, kbuf, vbuf,
                       (float*)nullptr, (const float*)nullptr);
    // fused attention
    hipLaunchKernelGGL(attn_kernel, dim3(1024), dim3(512), 0, stream,
                       qattn, kbuf, vbuf, attnO);
    // out = attnO @ Wo + bo
    hipLaunchKernelGGL(gemm_bt_kernel, dim3(4, 64), dim3(256), 0, stream,
                       attnO, WoT, 8192, 512, 1024, 2, (ushort_t*)nullptr, (ushort_t*)nullptr,
                       out, bo);
}

// Round 2
// 322.284 us; speedup vs baseline: 1.2893x; 1.2893x over previous
//
#include <hip/hip_runtime.h>
#include <stdint.h>

typedef unsigned short ushort_t;
typedef __attribute__((ext_vector_type(8))) short short8;
typedef __attribute__((ext_vector_type(4))) float floatx4;
typedef __attribute__((ext_vector_type(4))) float floatv4;
typedef __attribute__((ext_vector_type(4))) unsigned short ushortv4;

// B=64, I=128, J=512, H=16, D=64, QD=512, KVD=256, HID=1024

__device__ __forceinline__ ushort_t f2bf(float x) {
    union { float f; unsigned u; } v; v.f = x;
    unsigned r = v.u + 0x7fffu + ((v.u >> 16) & 1u);   // RNE
    return (ushort_t)(r >> 16);
}

// ---------------- cast fp32 -> bf16 (vectorized) ----------------
__global__ void cast_bf16_kernel(const float* __restrict__ src,
                                 ushort_t* __restrict__ dst, int n4) {
    int t = blockIdx.x * 256 + threadIdx.x;
    if (t >= n4) return;
    floatv4 v = ((const floatv4*)src)[t];
    ushortv4 o;
    o[0] = f2bf(v[0]); o[1] = f2bf(v[1]); o[2] = f2bf(v[2]); o[3] = f2bf(v[3]);
    ((ushortv4*)dst)[t] = o;
}

// ---------------- transpose+cast: W (K x N fp32) -> Wt (N x K bf16), scaled --
__global__ void tcast_kernel(const float* __restrict__ src,
                             ushort_t* __restrict__ dst, int K, int N, float scale) {
    int t = blockIdx.x * 256 + threadIdx.x;
    if (t >= K * N) return;
    int n = t / K, k = t - n * K;
    dst[t] = f2bf(src[k * N + n] * scale);
}

// ---------------- GEMM: C = A (MxK) * Bt^T, A,Bt bf16 row-major, Bt is NxK ---
// 128x128 tile, BK=64, 256 threads (2x2 waves), 16x16x32 bf16 MFMA.
// LDS tiles padded to stride 72 (144 B): fragment reads conflict-free.
// emode 0: staged row-major bf16 write to out_a, ld=1024          (qraw)
// emode 1: bx<8 -> staged row-major bf16 to out_a ld=1024 (kraw);
//          bx>=8 -> staged TRANSPOSED bf16 to out_b (vt: (b,h,d,j))
// emode 2: direct fp32 row-major + bias[col]
__global__ __launch_bounds__(256, 3) void gemm_bt_kernel(
    const ushort_t* __restrict__ A, const ushort_t* __restrict__ Bt,
    int M, int N, int K, int emode,
    ushort_t* __restrict__ out_a, ushort_t* __restrict__ out_b,
    float* __restrict__ out_f, const float* __restrict__ bias)
{
    __shared__ ushort_t smem[18432];          // 36.9 KB: sA|sB (2x128x72), reused as sT (128x132)
    ushort_t* sA = smem;
    ushort_t* sB = smem + 9216;
    ushort_t* sT = smem;                      // epilogue staging, stride 132

    const int tid  = threadIdx.x;
    const int lane = tid & 63;
    const int w    = tid >> 6;
    const int quad = lane >> 4;
    const int l15  = lane & 15;
    const int wr   = w >> 1, wc = w & 1;
    const int m0 = blockIdx.y * 128;
    const int n0 = blockIdx.x * 128;

    floatx4 acc[4][4];
#pragma unroll
    for (int i = 0; i < 4; i++)
#pragma unroll
        for (int j = 0; j < 4; j++) acc[i][j] = (floatx4){0.f, 0.f, 0.f, 0.f};

    for (int k0 = 0; k0 < K; k0 += 64) {
        __syncthreads();
#pragma unroll
        for (int i = 0; i < 4; i++) {
            int c = tid + i * 256;            // 0..1023
            int row = c >> 3, col = (c & 7) * 8;
            *(short8*)&sA[row * 72 + col] =
                *(const short8*)&A[(m0 + row) * K + k0 + col];
            *(short8*)&sB[row * 72 + col] =
                *(const short8*)&Bt[(n0 + row) * K + k0 + col];
        }
        __syncthreads();
#pragma unroll
        for (int ks = 0; ks < 64; ks += 32) {
            short8 af[4], bf[4];
#pragma unroll
            for (int i = 0; i < 4; i++)
                af[i] = *(const short8*)&sA[(wr * 64 + i * 16 + l15) * 72 + ks + quad * 8];
#pragma unroll
            for (int j = 0; j < 4; j++)
                bf[j] = *(const short8*)&sB[(wc * 64 + j * 16 + l15) * 72 + ks + quad * 8];
#pragma unroll
            for (int i = 0; i < 4; i++)
#pragma unroll
                for (int j = 0; j < 4; j++)
                    acc[i][j] = __builtin_amdgcn_mfma_f32_16x16x32_bf16(
                        af[i], bf[j], acc[i][j], 0, 0, 0);
        }
    }

    // C layout: row = quad*4+r, col = lane&15 (verified m89/m91)
    if (emode == 2) {
#pragma unroll
        for (int i = 0; i < 4; i++)
#pragma unroll
            for (int j = 0; j < 4; j++)
#pragma unroll
                for (int r = 0; r < 4; r++) {
                    int grow = m0 + wr * 64 + i * 16 + quad * 4 + r;
                    int gcol = n0 + wc * 64 + j * 16 + l15;
                    out_f[grow * N + gcol] = acc[i][j][r] + bias[gcol];
                }
        return;
    }

    __syncthreads();   // all fragment reads of sA/sB done; smem reusable
    const bool vtrans = (emode == 1) && (n0 >= 1024);
    if (vtrans) {
        // stage transposed: sT[col][row], b64-packed along r
#pragma unroll
        for (int i = 0; i < 4; i++)
#pragma unroll
            for (int j = 0; j < 4; j++) {
                int col = wc * 64 + j * 16 + l15;
                int rowb = wr * 64 + i * 16 + quad * 4;
                ushortv4 p;
#pragma unroll
                for (int r = 0; r < 4; r++) p[r] = f2bf(acc[i][j][r]);
                *(ushortv4*)&sT[col * 132 + rowb] = p;
            }
        __syncthreads();
        // coalesced write: vt[(b*16+h)*64 + d][512 j's]
        int b = m0 >> 9, j0 = m0 & 511;
#pragma unroll
        for (int it = 0; it < 8; it++) {
            int idx = it * 256 + tid;
            int drow = idx >> 4, chunk = idx & 15;
            short8 v = *(const short8*)&sT[drow * 132 + chunk * 8];
            int dcomp = (n0 - 1024) + drow;
            int h = dcomp >> 6, d = dcomp & 63;
            *(short8*)&out_b[(((size_t)(b * 16 + h) * 64 + d) << 9) + j0 + chunk * 8] = v;
        }
    } else {
        // stage row-major: sT[row][col]
#pragma unroll
        for (int i = 0; i < 4; i++)
#pragma unroll
            for (int j = 0; j < 4; j++)
#pragma unroll
                for (int r = 0; r < 4; r++) {
                    int row = wr * 64 + i * 16 + quad * 4 + r;
                    int col = wc * 64 + j * 16 + l15;
                    sT[row * 132 + col] = f2bf(acc[i][j][r]);
                }
        __syncthreads();
#pragma unroll
        for (int it = 0; it < 8; it++) {
            int idx = it * 256 + tid;
            int row = idx >> 4, chunk = idx & 15;
            short8 v = *(const short8*)&sT[row * 132 + chunk * 8];
            *(short8*)&out_a[(size_t)(m0 + row) * 1024 + n0 + chunk * 8] = v;
        }
    }
}

// ---------------- fused attention v2 (flash over 4 j-chunks of 128) --------
// grid = B*H = 1024 blocks, 512 threads (8 waves). Wave w owns i-tile w (16 rows).
// LDS: sK 128x72 (18.4KB) + sVt 64x136 (17.4KB) + sP 8x(16x136) (34.8KB) = 69KB
//      -> 2 blocks/CU. All padded strides: MFMA fragment reads conflict-free.
__global__ __launch_bounds__(512, 4) void attn_kernel(
    const ushort_t* __restrict__ Q,    // qraw (b*128+i, 1024)
    const ushort_t* __restrict__ Kr,   // kraw (b*512+j, 1024)
    const ushort_t* __restrict__ Vt,   // (b*16+h)*64+d, 512 j's
    ushort_t* __restrict__ O)          // (b*128+i, 1024)
{
    __shared__ ushort_t sK[128 * 72];
    __shared__ ushort_t sVt[64 * 136];
    __shared__ ushort_t sP[8 * 16 * 136];

    const int bh = blockIdx.x;
    const int b = bh >> 4, h = bh & 15;
    const int tid  = threadIdx.x;
    const int lane = tid & 63, w = tid >> 6;
    const int quad = lane >> 4, l15 = lane & 15;
    const int i0 = w * 16;

    // Q fragments (A-layout: m=lane&15, k=quad*8+e), reused for all chunks
    const ushort_t* qrow = &Q[(size_t)(b * 128 + i0 + l15) * 1024 + h * 64 + quad * 8];
    short8 aq0 = *(const short8*)qrow;
    short8 aq1 = *(const short8*)(qrow + 32);

    float mrow[4], lrow[4];
    floatx4 acc_o[4];
#pragma unroll
    for (int r = 0; r < 4; r++) { mrow[r] = -1e30f; lrow[r] = 0.f; }
#pragma unroll
    for (int dt = 0; dt < 4; dt++) acc_o[dt] = (floatx4){0.f, 0.f, 0.f, 0.f};

    ushort_t* sp = &sP[w * 2176];

    for (int c4 = 0; c4 < 4; c4++) {
        const int j0 = c4 * 128;
        __syncthreads();
        // stage K chunk (128 x 64) and Vt chunk (64 x 128)
#pragma unroll
        for (int t = 0; t < 2; t++) {
            int cc = tid + t * 512;
            int row = cc >> 3, c8 = cc & 7;
            *(short8*)&sK[row * 72 + c8 * 8] =
                *(const short8*)&Kr[(size_t)(b * 512 + j0 + row) * 1024 + h * 64 + c8 * 8];
        }
#pragma unroll
        for (int t = 0; t < 2; t++) {
            int cc = tid + t * 512;
            int drow = cc >> 4, c8 = cc & 15;
            *(short8*)&sVt[drow * 136 + c8 * 8] =
                *(const short8*)&Vt[(((size_t)bh * 64 + drow) << 9) + j0 + c8 * 8];
        }
        __syncthreads();

        // S chunk = Q * K^T (16 x 128) in registers
        floatx4 s[8];
#pragma unroll
        for (int jt = 0; jt < 8; jt++) {
            const ushort_t* kp = &sK[(jt * 16 + l15) * 72 + quad * 8];
            short8 bk0 = *(const short8*)kp;
            short8 bk1 = *(const short8*)(kp + 32);
            floatx4 a = (floatx4){0.f, 0.f, 0.f, 0.f};
            a = __builtin_amdgcn_mfma_f32_16x16x32_bf16(aq0, bk0, a, 0, 0, 0);
            a = __builtin_amdgcn_mfma_f32_16x16x32_bf16(aq1, bk1, a, 0, 0, 0);
            s[jt] = a;
        }

        // online softmax (rows live in (quad,r); 16 l15-lanes share a row)
#pragma unroll
        for (int r = 0; r < 4; r++) {
            float mx = s[0][r];
#pragma unroll
            for (int jt = 1; jt < 8; jt++) mx = fmaxf(mx, s[jt][r]);
#pragma unroll
            for (int off = 1; off < 16; off <<= 1) mx = fmaxf(mx, __shfl_xor(mx, off));
            float mnew = fmaxf(mrow[r], mx);
            float alpha = __expf(mrow[r] - mnew);
            mrow[r] = mnew;
            float psum = 0.f;
#pragma unroll
            for (int jt = 0; jt < 8; jt++) {
                float p = __expf(s[jt][r] - mnew);
                s[jt][r] = p;
                psum += p;
            }
#pragma unroll
            for (int off = 1; off < 16; off <<= 1) psum += __shfl_xor(psum, off);
            lrow[r] = lrow[r] * alpha + psum;
#pragma unroll
            for (int dt = 0; dt < 4; dt++) acc_o[dt][r] *= alpha;
        }

        // P -> per-wave LDS buffer (no barrier needed: private per wave)
#pragma unroll
        for (int jt = 0; jt < 8; jt++)
#pragma unroll
            for (int r = 0; r < 4; r++)
                sp[(quad * 4 + r) * 136 + jt * 16 + l15] = f2bf(s[jt][r]);

        // O += P * V
#pragma unroll
        for (int kk = 0; kk < 4; kk++) {
            short8 ap = *(const short8*)&sp[l15 * 136 + kk * 32 + quad * 8];
#pragma unroll
            for (int dt = 0; dt < 4; dt++) {
                short8 bv = *(const short8*)&sVt[(dt * 16 + l15) * 136 + kk * 32 + quad * 8];
                acc_o[dt] = __builtin_amdgcn_mfma_f32_16x16x32_bf16(ap, bv, acc_o[dt], 0, 0, 0);
            }
        }
    }

    // epilogue: normalize and write (b*128+i, h*64+d)
#pragma unroll
    for (int r = 0; r < 4; r++) {
        float inv = 1.0f / lrow[r];
        size_t rowo = (size_t)(b * 128 + i0 + quad * 4 + r) * 1024 + h * 64;
#pragma unroll
        for (int dt = 0; dt < 4; dt++)
            O[rowo + dt * 16 + l15] = f2bf(acc_o[dt][r] * inv);
    }
}

// ---------------- launch ----------------
extern "C" void kernel_launch(void* const* d_in, const int* in_sizes, int n_in,
                              void* d_out, int out_size, void* d_ws, size_t ws_size,
                              hipStream_t stream) {
    const float* q   = (const float*)d_in[0];   // (64,128,512)
    const float* kv  = (const float*)d_in[1];   // (64,512,256)
    const float* Wq  = (const float*)d_in[2];   // (512,1024)
    const float* Wkv = (const float*)d_in[3];   // (256,2048)
    const float* Wo  = (const float*)d_in[4];   // (1024,512)
    const float* bo  = (const float*)d_in[5];   // (512,)
    float* out = (float*)d_out;

    char* ws = (char*)d_ws;
    ushort_t* qA    = (ushort_t*)(ws + 0);          //  8 MB  (8192 x 512)
    ushort_t* kvA   = (ushort_t*)(ws + 8388608);    // 16 MB  (32768 x 256)
    ushort_t* WqT   = (ushort_t*)(ws + 25165824);   //  1 MB  (1024 x 512)
    ushort_t* WkvT  = (ushort_t*)(ws + 26214400);   //  1 MB  (2048 x 256)
    ushort_t* WoT   = (ushort_t*)(ws + 27262976);   //  1 MB  (512 x 1024)
    ushort_t* qraw  = (ushort_t*)(ws + 28311552);   // 16 MB  (8192 x 1024)
    ushort_t* kraw  = (ushort_t*)(ws + 45088768);   // 64 MB  (32768 x 1024)
    ushort_t* vt    = (ushort_t*)(ws + 112197632);  // 64 MB  ((b,h,d) x 512)
    ushort_t* attnO = (ushort_t*)(ws + 179306496);  // 16 MB  (8192 x 1024)

    const float scale = 0.125f;  // HEAD_DIM^-0.5, folded into Wq

    hipLaunchKernelGGL(cast_bf16_kernel, dim3(4096), dim3(256), 0, stream, q,  qA,  4194304 / 4);
    hipLaunchKernelGGL(cast_bf16_kernel, dim3(8192), dim3(256), 0, stream, kv, kvA, 8388608 / 4);
    hipLaunchKernelGGL(tcast_kernel, dim3(2048), dim3(256), 0, stream, Wq,  WqT,  512,  1024, scale);
    hipLaunchKernelGGL(tcast_kernel, dim3(2048), dim3(256), 0, stream, Wkv, WkvT, 256,  2048, 1.0f);
    hipLaunchKernelGGL(tcast_kernel, dim3(2048), dim3(256), 0, stream, Wo,  WoT,  1024, 512,  1.0f);

    // qraw = (q @ Wq) * scale, row-major bf16
    hipLaunchKernelGGL(gemm_bt_kernel, dim3(8, 64), dim3(256), 0, stream,
                       qA, WqT, 8192, 1024, 512, 0, qraw, (ushort_t*)nullptr,
                       (float*)nullptr, (const float*)nullptr);
    // kraw (row-major) + vt (transposed) = kv @ Wkv
    hipLaunchKernelGGL(gemm_bt_kernel, dim3(16, 256), dim3(256), 0, stream,
                       kvA, WkvT, 32768, 2048, 256, 1, kraw, vt,
                       (float*)nullptr, (const float*)nullptr);
    // fused attention
    hipLaunchKernelGGL(attn_kernel, dim3(1024), dim3(512), 0, stream,
                       qraw, kraw, vt, attnO);
    // out = attnO @ Wo + bo
    hipLaunchKernelGGL(gemm_bt_kernel, dim3(4, 64), dim3(256), 0, stream,
                       attnO, WoT, 8192, 512, 1024, 2, (ushort_t*)nullptr, (ushort_t*)nullptr,
                       out, bo);
}

// Round 3
// 277.892 us; speedup vs baseline: 1.4953x; 1.1597x over previous
//
#include <hip/hip_runtime.h>
#include <stdint.h>

typedef unsigned short ushort_t;
typedef __attribute__((ext_vector_type(8))) short short8;
typedef __attribute__((ext_vector_type(4))) float floatx4;
typedef __attribute__((ext_vector_type(4))) float floatv4;
typedef __attribute__((ext_vector_type(4))) unsigned short ushortv4;

// B=64, I=128, J=512, H=16, D=64, QD=512, KVD=256, HID=1024

__device__ __forceinline__ ushort_t f2bf(float x) {
    union { float f; unsigned u; } v; v.f = x;
    unsigned r = v.u + 0x7fffu + ((v.u >> 16) & 1u);   // RNE
    return (ushort_t)(r >> 16);
}

// async global->LDS, 16B per lane; LDS dst = wave-uniform base + lane*16
__device__ __forceinline__ void gl_lds16(const ushort_t* g, ushort_t* l) {
    __builtin_amdgcn_global_load_lds(
        (const __attribute__((address_space(1))) void*)g,
        (__attribute__((address_space(3))) void*)l, 16, 0, 0);
}

// ---------------- cast fp32 -> bf16 (vectorized) ----------------
__global__ void cast_bf16_kernel(const float* __restrict__ src,
                                 ushort_t* __restrict__ dst, int n4) {
    int t = blockIdx.x * 256 + threadIdx.x;
    if (t >= n4) return;
    floatv4 v = ((const floatv4*)src)[t];
    ushortv4 o;
    o[0] = f2bf(v[0]); o[1] = f2bf(v[1]); o[2] = f2bf(v[2]); o[3] = f2bf(v[3]);
    ((ushortv4*)dst)[t] = o;
}

// ---------------- transpose+cast: W (K x N fp32) -> Wt (N x K bf16), scaled --
__global__ void tcast_kernel(const float* __restrict__ src,
                             ushort_t* __restrict__ dst, int K, int N, float scale) {
    int t = blockIdx.x * 256 + threadIdx.x;
    if (t >= K * N) return;
    int n = t / K, k = t - n * K;
    dst[t] = f2bf(src[k * N + n] * scale);
}

// ---------------- GEMM: C = A (MxK) * Bt^T, A,Bt bf16 row-major, Bt is NxK ---
// 128x128 tile, BK=64, 256 threads (2x2 waves), 16x16x32 bf16 MFMA.
// m97 structure: global_load_lds width-16 staging into UNPADDED stride-64 tiles.
// 1D grid + XCD-band swizzle: xcd = bid&7 owns a contiguous m-band (L2 reuse).
// emode 0: staged row-major bf16 write to out_a, ld=1024          (qraw)
// emode 1: x<8 -> staged row-major bf16 to out_a ld=1024 (kraw);
//          x>=8 -> staged TRANSPOSED bf16 to out_b (vt: (b,h,d,j))
// emode 2: direct fp32 row-major + bias[col]
__global__ __launch_bounds__(256, 3) void gemm_bt_kernel(
    const ushort_t* __restrict__ A, const ushort_t* __restrict__ Bt,
    int M, int N, int K, int gx, int gy, int emode,
    ushort_t* __restrict__ out_a, ushort_t* __restrict__ out_b,
    float* __restrict__ out_f, const float* __restrict__ bias)
{
    __shared__ ushort_t smem[16896];          // sA|sB: 2 x 128x64 (32KB); sT: 128x132 (33.8KB)
    ushort_t* sA = smem;
    ushort_t* sB = smem + 8192;
    ushort_t* sT = smem;

    // XCD-band swizzle: same-XCD blocks share a contiguous y-band
    const int bid  = blockIdx.x;
    const int xcd  = bid & 7;
    const int slot = bid >> 3;
    const int band = gy >> 3;                 // y-rows per XCD
    const int by   = xcd * band + slot % band;
    const int bx   = slot / band;

    const int tid  = threadIdx.x;
    const int lane = tid & 63;
    const int w    = tid >> 6;
    const int quad = lane >> 4;
    const int l15  = lane & 15;
    const int wr   = w >> 1, wc = w & 1;
    const int m0 = by * 128;
    const int n0 = bx * 128;

    const int rsub = lane >> 3;               // 0..7 row within 8-row group
    const int c8   = lane & 7;                // 16B chunk within row
    const int wrow = w * 32;                  // rows staged by this wave

    floatx4 acc[4][4];
#pragma unroll
    for (int i = 0; i < 4; i++)
#pragma unroll
        for (int j = 0; j < 4; j++) acc[i][j] = (floatx4){0.f, 0.f, 0.f, 0.f};

    for (int k0 = 0; k0 < K; k0 += 64) {
        __syncthreads();
#pragma unroll
        for (int t = 0; t < 4; t++) {
            int rg = wrow + t * 8;            // wave-uniform row-group base
            gl_lds16(&A[(size_t)(m0 + rg + rsub) * K + k0 + c8 * 8], &sA[rg * 64]);
            gl_lds16(&Bt[(size_t)(n0 + rg + rsub) * K + k0 + c8 * 8], &sB[rg * 64]);
        }
        __syncthreads();                      // waits vmcnt(0): LDS writes landed
#pragma unroll
        for (int ks = 0; ks < 64; ks += 32) {
            short8 af[4], bf[4];
#pragma unroll
            for (int i = 0; i < 4; i++)
                af[i] = *(const short8*)&sA[(wr * 64 + i * 16 + l15) * 64 + ks + quad * 8];
#pragma unroll
            for (int j = 0; j < 4; j++)
                bf[j] = *(const short8*)&sB[(wc * 64 + j * 16 + l15) * 64 + ks + quad * 8];
#pragma unroll
            for (int i = 0; i < 4; i++)
#pragma unroll
                for (int j = 0; j < 4; j++)
                    acc[i][j] = __builtin_amdgcn_mfma_f32_16x16x32_bf16(
                        af[i], bf[j], acc[i][j], 0, 0, 0);
        }
    }

    // C layout: row = quad*4+r, col = lane&15 (verified m89/m91)
    if (emode == 2) {
#pragma unroll
        for (int i = 0; i < 4; i++)
#pragma unroll
            for (int j = 0; j < 4; j++)
#pragma unroll
                for (int r = 0; r < 4; r++) {
                    int grow = m0 + wr * 64 + i * 16 + quad * 4 + r;
                    int gcol = n0 + wc * 64 + j * 16 + l15;
                    out_f[(size_t)grow * N + gcol] = acc[i][j][r] + bias[gcol];
                }
        return;
    }

    __syncthreads();   // all fragment reads of sA/sB done; smem reusable
    const bool vtrans = (emode == 1) && (n0 >= 1024);
    if (vtrans) {
        // stage transposed: sT[col][row], b64-packed along r
#pragma unroll
        for (int i = 0; i < 4; i++)
#pragma unroll
            for (int j = 0; j < 4; j++) {
                int col = wc * 64 + j * 16 + l15;
                int rowb = wr * 64 + i * 16 + quad * 4;
                ushortv4 p;
#pragma unroll
                for (int r = 0; r < 4; r++) p[r] = f2bf(acc[i][j][r]);
                *(ushortv4*)&sT[col * 132 + rowb] = p;
            }
        __syncthreads();
        // coalesced write: vt[(b*16+h)*64 + d][512 j's]
        int b = m0 >> 9, j0 = m0 & 511;
#pragma unroll
        for (int it = 0; it < 8; it++) {
            int idx = it * 256 + tid;
            int drow = idx >> 4, chunk = idx & 15;
            short8 v = *(const short8*)&sT[drow * 132 + chunk * 8];
            int dcomp = (n0 - 1024) + drow;
            int h = dcomp >> 6, d = dcomp & 63;
            *(short8*)&out_b[(((size_t)(b * 16 + h) * 64 + d) << 9) + j0 + chunk * 8] = v;
        }
    } else {
        // stage row-major: sT[row][col]
#pragma unroll
        for (int i = 0; i < 4; i++)
#pragma unroll
            for (int j = 0; j < 4; j++)
#pragma unroll
                for (int r = 0; r < 4; r++) {
                    int row = wr * 64 + i * 16 + quad * 4 + r;
                    int col = wc * 64 + j * 16 + l15;
                    sT[row * 132 + col] = f2bf(acc[i][j][r]);
                }
        __syncthreads();
#pragma unroll
        for (int it = 0; it < 8; it++) {
            int idx = it * 256 + tid;
            int row = idx >> 4, chunk = idx & 15;
            short8 v = *(const short8*)&sT[row * 132 + chunk * 8];
            *(short8*)&out_a[(size_t)(m0 + row) * 1024 + n0 + chunk * 8] = v;
        }
    }
}

// ---------------- fused attention v2 (flash over 4 j-chunks of 128) --------
// grid = B*H = 1024 blocks, 512 threads (8 waves). Wave w owns i-tile w (16 rows).
// LDS: sK 128x72 (18.4KB) + sVt 64x136 (17.4KB) + sP 8x(16x136) (34.8KB) = 69KB
//      -> 2 blocks/CU. All padded strides: MFMA fragment reads conflict-free.
__global__ __launch_bounds__(512, 4) void attn_kernel(
    const ushort_t* __restrict__ Q,    // qraw (b*128+i, 1024)
    const ushort_t* __restrict__ Kr,   // kraw (b*512+j, 1024)
    const ushort_t* __restrict__ Vt,   // (b*16+h)*64+d, 512 j's
    ushort_t* __restrict__ O)          // (b*128+i, 1024)
{
    __shared__ ushort_t sK[128 * 72];
    __shared__ ushort_t sVt[64 * 136];
    __shared__ ushort_t sP[8 * 16 * 136];

    const int bh = blockIdx.x;
    const int b = bh >> 4, h = bh & 15;
    const int tid  = threadIdx.x;
    const int lane = tid & 63, w = tid >> 6;
    const int quad = lane >> 4, l15 = lane & 15;
    const int i0 = w * 16;

    // Q fragments (A-layout: m=lane&15, k=quad*8+e), reused for all chunks
    const ushort_t* qrow = &Q[(size_t)(b * 128 + i0 + l15) * 1024 + h * 64 + quad * 8];
    short8 aq0 = *(const short8*)qrow;
    short8 aq1 = *(const short8*)(qrow + 32);

    float mrow[4], lrow[4];
    floatx4 acc_o[4];
#pragma unroll
    for (int r = 0; r < 4; r++) { mrow[r] = -1e30f; lrow[r] = 0.f; }
#pragma unroll
    for (int dt = 0; dt < 4; dt++) acc_o[dt] = (floatx4){0.f, 0.f, 0.f, 0.f};

    ushort_t* sp = &sP[w * 2176];

    for (int c4 = 0; c4 < 4; c4++) {
        const int j0 = c4 * 128;
        __syncthreads();
        // stage K chunk (128 x 64) and Vt chunk (64 x 128)
#pragma unroll
        for (int t = 0; t < 2; t++) {
            int cc = tid + t * 512;
            int row = cc >> 3, c8 = cc & 7;
            *(short8*)&sK[row * 72 + c8 * 8] =
                *(const short8*)&Kr[(size_t)(b * 512 + j0 + row) * 1024 + h * 64 + c8 * 8];
        }
#pragma unroll
        for (int t = 0; t < 2; t++) {
            int cc = tid + t * 512;
            int drow = cc >> 4, c8 = cc & 15;
            *(short8*)&sVt[drow * 136 + c8 * 8] =
                *(const short8*)&Vt[(((size_t)bh * 64 + drow) << 9) + j0 + c8 * 8];
        }
        __syncthreads();

        // S chunk = Q * K^T (16 x 128) in registers
        floatx4 s[8];
#pragma unroll
        for (int jt = 0; jt < 8; jt++) {
            const ushort_t* kp = &sK[(jt * 16 + l15) * 72 + quad * 8];
            short8 bk0 = *(const short8*)kp;
            short8 bk1 = *(const short8*)(kp + 32);
            floatx4 a = (floatx4){0.f, 0.f, 0.f, 0.f};
            a = __builtin_amdgcn_mfma_f32_16x16x32_bf16(aq0, bk0, a, 0, 0, 0);
            a = __builtin_amdgcn_mfma_f32_16x16x32_bf16(aq1, bk1, a, 0, 0, 0);
            s[jt] = a;
        }

        // online softmax (rows live in (quad,r); 16 l15-lanes share a row)
#pragma unroll
        for (int r = 0; r < 4; r++) {
            float mx = s[0][r];
#pragma unroll
            for (int jt = 1; jt < 8; jt++) mx = fmaxf(mx, s[jt][r]);
#pragma unroll
            for (int off = 1; off < 16; off <<= 1) mx = fmaxf(mx, __shfl_xor(mx, off));
            float mnew = fmaxf(mrow[r], mx);
            float alpha = __expf(mrow[r] - mnew);
            mrow[r] = mnew;
            float psum = 0.f;
#pragma unroll
            for (int jt = 0; jt < 8; jt++) {
                float p = __expf(s[jt][r] - mnew);
                s[jt][r] = p;
                psum += p;
            }
#pragma unroll
            for (int off = 1; off < 16; off <<= 1) psum += __shfl_xor(psum, off);
            lrow[r] = lrow[r] * alpha + psum;
#pragma unroll
            for (int dt = 0; dt < 4; dt++) acc_o[dt][r] *= alpha;
        }

        // P -> per-wave LDS buffer (no barrier needed: private per wave)
#pragma unroll
        for (int jt = 0; jt < 8; jt++)
#pragma unroll
            for (int r = 0; r < 4; r++)
                sp[(quad * 4 + r) * 136 + jt * 16 + l15] = f2bf(s[jt][r]);

        // O += P * V
#pragma unroll
        for (int kk = 0; kk < 4; kk++) {
            short8 ap = *(const short8*)&sp[l15 * 136 + kk * 32 + quad * 8];
#pragma unroll
            for (int dt = 0; dt < 4; dt++) {
                short8 bv = *(const short8*)&sVt[(dt * 16 + l15) * 136 + kk * 32 + quad * 8];
                acc_o[dt] = __builtin_amdgcn_mfma_f32_16x16x32_bf16(ap, bv, acc_o[dt], 0, 0, 0);
            }
        }
    }

    // epilogue: normalize and write (b*128+i, h*64+d)
#pragma unroll
    for (int r = 0; r < 4; r++) {
        float inv = 1.0f / lrow[r];
        size_t rowo = (size_t)(b * 128 + i0 + quad * 4 + r) * 1024 + h * 64;
#pragma unroll
        for (int dt = 0; dt < 4; dt++)
            O[rowo + dt * 16 + l15] = f2bf(acc_o[dt][r] * inv);
    }
}

// ---------------- launch ----------------
extern "C" void kernel_launch(void* const* d_in, const int* in_sizes, int n_in,
                              void* d_out, int out_size, void* d_ws, size_t ws_size,
                              hipStream_t stream) {
    const float* q   = (const float*)d_in[0];   // (64,128,512)
    const float* kv  = (const float*)d_in[1];   // (64,512,256)
    const float* Wq  = (const float*)d_in[2];   // (512,1024)
    const float* Wkv = (const float*)d_in[3];   // (256,2048)
    const float* Wo  = (const float*)d_in[4];   // (1024,512)
    const float* bo  = (const float*)d_in[5];   // (512,)
    float* out = (float*)d_out;

    char* ws = (char*)d_ws;
    ushort_t* qA    = (ushort_t*)(ws + 0);          //  8 MB  (8192 x 512)
    ushort_t* kvA   = (ushort_t*)(ws + 8388608);    // 16 MB  (32768 x 256)
    ushort_t* WqT   = (ushort_t*)(ws + 25165824);   //  1 MB  (1024 x 512)
    ushort_t* WkvT  = (ushort_t*)(ws + 26214400);   //  1 MB  (2048 x 256)
    ushort_t* WoT   = (ushort_t*)(ws + 27262976);   //  1 MB  (512 x 1024)
    ushort_t* qraw  = (ushort_t*)(ws + 28311552);   // 16 MB  (8192 x 1024)
    ushort_t* kraw  = (ushort_t*)(ws + 45088768);   // 64 MB  (32768 x 1024)
    ushort_t* vt    = (ushort_t*)(ws + 112197632);  // 64 MB  ((b,h,d) x 512)
    ushort_t* attnO = (ushort_t*)(ws + 179306496);  // 16 MB  (8192 x 1024)

    const float scale = 0.125f;  // HEAD_DIM^-0.5, folded into Wq

    hipLaunchKernelGGL(cast_bf16_kernel, dim3(4096), dim3(256), 0, stream, q,  qA,  4194304 / 4);
    hipLaunchKernelGGL(cast_bf16_kernel, dim3(8192), dim3(256), 0, stream, kv, kvA, 8388608 / 4);
    hipLaunchKernelGGL(tcast_kernel, dim3(2048), dim3(256), 0, stream, Wq,  WqT,  512,  1024, scale);
    hipLaunchKernelGGL(tcast_kernel, dim3(2048), dim3(256), 0, stream, Wkv, WkvT, 256,  2048, 1.0f);
    hipLaunchKernelGGL(tcast_kernel, dim3(2048), dim3(256), 0, stream, Wo,  WoT,  1024, 512,  1.0f);

    // qraw = (q @ Wq) * scale, row-major bf16   [gx=8, gy=64]
    hipLaunchKernelGGL(gemm_bt_kernel, dim3(512), dim3(256), 0, stream,
                       qA, WqT, 8192, 1024, 512, 8, 64, 0, qraw, (ushort_t*)nullptr,
                       (float*)nullptr, (const float*)nullptr);
    // kraw (row-major) + vt (transposed) = kv @ Wkv   [gx=16, gy=256]
    hipLaunchKernelGGL(gemm_bt_kernel, dim3(4096), dim3(256), 0, stream,
                       kvA, WkvT, 32768, 2048, 256, 16, 256, 1, kraw, vt,
                       (float*)nullptr, (const float*)nullptr);
    // fused attention
    hipLaunchKernelGGL(attn_kernel, dim3(1024), dim3(512), 0, stream,
                       qraw, kraw, vt, attnO);
    // out = attnO @ Wo + bo   [gx=4, gy=64]
    hipLaunchKernelGGL(gemm_bt_kernel, dim3(256), dim3(256), 0, stream,
                       attnO, WoT, 8192, 512, 1024, 4, 64, 2, (ushort_t*)nullptr, (ushort_t*)nullptr,
                       out, bo);
}

// Round 4
// 270.977 us; speedup vs baseline: 1.5334x; 1.0255x over previous
//
#include <hip/hip_runtime.h>
#include <stdint.h>

typedef unsigned short ushort_t;
typedef __attribute__((ext_vector_type(8))) short short8;
typedef __attribute__((ext_vector_type(4))) float floatx4;
typedef __attribute__((ext_vector_type(4))) float floatv4;
typedef __attribute__((ext_vector_type(4))) unsigned short ushortv4;

// B=64, I=128, J=512, H=16, D=64, QD=512, KVD=256, HID=1024

__device__ __forceinline__ ushort_t f2bf(float x) {
    union { float f; unsigned u; } v; v.f = x;
    unsigned r = v.u + 0x7fffu + ((v.u >> 16) & 1u);   // RNE
    return (ushort_t)(r >> 16);
}

// async global->LDS, 16B per lane; LDS dst = wave-uniform base + lane*16
__device__ __forceinline__ void gl_lds16(const ushort_t* g, ushort_t* l) {
    __builtin_amdgcn_global_load_lds(
        (const __attribute__((address_space(1))) void*)g,
        (__attribute__((address_space(3))) void*)l, 16, 0, 0);
}

// ---------------- cast fp32 -> bf16 (vectorized) ----------------
__global__ void cast_bf16_kernel(const float* __restrict__ src,
                                 ushort_t* __restrict__ dst, int n4) {
    int t = blockIdx.x * 256 + threadIdx.x;
    if (t >= n4) return;
    floatv4 v = ((const floatv4*)src)[t];
    ushortv4 o;
    o[0] = f2bf(v[0]); o[1] = f2bf(v[1]); o[2] = f2bf(v[2]); o[3] = f2bf(v[3]);
    ((ushortv4*)dst)[t] = o;
}

// ---------------- transpose+cast: W (K x N fp32) -> Wt (N x K bf16), scaled --
__global__ void tcast_kernel(const float* __restrict__ src,
                             ushort_t* __restrict__ dst, int K, int N, float scale) {
    int t = blockIdx.x * 256 + threadIdx.x;
    if (t >= K * N) return;
    int n = t / K, k = t - n * K;
    dst[t] = f2bf(src[k * N + n] * scale);
}

// ---------------- GEMM: C = A (MxK) * Bt^T (m97-style), for q-proj & o-proj --
// 128x128 tile, BK=64, 256 threads (2x2 waves), 16x16x32 bf16 MFMA.
// global_load_lds width-16 staging, unpadded stride-64 tiles, XCD-band swizzle.
// emode 0: staged row-major bf16 write to out_a, ld=1024
// emode 2: direct fp32 row-major + bias[col]
__global__ __launch_bounds__(256, 3) void gemm_bt_kernel(
    const ushort_t* __restrict__ A, const ushort_t* __restrict__ Bt,
    int M, int N, int K, int gx, int gy, int emode,
    ushort_t* __restrict__ out_a,
    float* __restrict__ out_f, const float* __restrict__ bias)
{
    __shared__ ushort_t smem[16896];          // sA|sB: 2 x 128x64 (32KB); sT: 128x132
    ushort_t* sA = smem;
    ushort_t* sB = smem + 8192;
    ushort_t* sT = smem;

    const int bid  = blockIdx.x;
    const int xcd  = bid & 7;
    const int slot = bid >> 3;
    const int band = gy >> 3;
    const int by   = xcd * band + slot % band;
    const int bx   = slot / band;

    const int tid  = threadIdx.x;
    const int lane = tid & 63;
    const int w    = tid >> 6;
    const int quad = lane >> 4;
    const int l15  = lane & 15;
    const int wr   = w >> 1, wc = w & 1;
    const int m0 = by * 128;
    const int n0 = bx * 128;

    const int rsub = lane >> 3;
    const int c8   = lane & 7;
    const int wrow = w * 32;

    floatx4 acc[4][4];
#pragma unroll
    for (int i = 0; i < 4; i++)
#pragma unroll
        for (int j = 0; j < 4; j++) acc[i][j] = (floatx4){0.f, 0.f, 0.f, 0.f};

    for (int k0 = 0; k0 < K; k0 += 64) {
        __syncthreads();
#pragma unroll
        for (int t = 0; t < 4; t++) {
            int rg = wrow + t * 8;
            gl_lds16(&A[(size_t)(m0 + rg + rsub) * K + k0 + c8 * 8], &sA[rg * 64]);
            gl_lds16(&Bt[(size_t)(n0 + rg + rsub) * K + k0 + c8 * 8], &sB[rg * 64]);
        }
        __syncthreads();
#pragma unroll
        for (int ks = 0; ks < 64; ks += 32) {
            short8 af[4], bf[4];
#pragma unroll
            for (int i = 0; i < 4; i++)
                af[i] = *(const short8*)&sA[(wr * 64 + i * 16 + l15) * 64 + ks + quad * 8];
#pragma unroll
            for (int j = 0; j < 4; j++)
                bf[j] = *(const short8*)&sB[(wc * 64 + j * 16 + l15) * 64 + ks + quad * 8];
#pragma unroll
            for (int i = 0; i < 4; i++)
#pragma unroll
                for (int j = 0; j < 4; j++)
                    acc[i][j] = __builtin_amdgcn_mfma_f32_16x16x32_bf16(
                        af[i], bf[j], acc[i][j], 0, 0, 0);
        }
    }

    // C layout: row = quad*4+r, col = lane&15 (verified m89/m91)
    if (emode == 2) {
#pragma unroll
        for (int i = 0; i < 4; i++)
#pragma unroll
            for (int j = 0; j < 4; j++)
#pragma unroll
                for (int r = 0; r < 4; r++) {
                    int grow = m0 + wr * 64 + i * 16 + quad * 4 + r;
                    int gcol = n0 + wc * 64 + j * 16 + l15;
                    out_f[(size_t)grow * N + gcol] = acc[i][j][r] + bias[gcol];
                }
        return;
    }

    __syncthreads();
#pragma unroll
    for (int i = 0; i < 4; i++)
#pragma unroll
        for (int j = 0; j < 4; j++)
#pragma unroll
            for (int r = 0; r < 4; r++) {
                int row = wr * 64 + i * 16 + quad * 4 + r;
                int col = wc * 64 + j * 16 + l15;
                sT[row * 132 + col] = f2bf(acc[i][j][r]);
            }
    __syncthreads();
#pragma unroll
    for (int it = 0; it < 8; it++) {
        int idx = it * 256 + tid;
        int row = idx >> 4, chunk = idx & 15;
        short8 v = *(const short8*)&sT[row * 132 + chunk * 8];
        *(short8*)&out_a[(size_t)(m0 + row) * 1024 + n0 + chunk * 8] = v;
    }
}

// ---------------- fused KV-projection + flash attention ----------------
// grid = B*H = 1024 blocks, 512 threads (8 waves), 1 block/CU (107.5 KB LDS).
// Per j-chunk of 128: project Kc = kv_chunk @ Wk_slice^T and Vc (to LDS only),
// then S = Q*Kc^T, online softmax, O += P*Vc. W-slice frags live in registers.
// Proj wave map: (wr=w>>2, wc=w&3) -> 64j x 32n tile. Attn wave map: i-tile w.
__global__ __launch_bounds__(512, 2) void fattn_kernel(
    const ushort_t* __restrict__ Q,    // qraw (b*128+i, 1024)
    const ushort_t* __restrict__ KV,   // kvA  (b*512+j, 256)
    const ushort_t* __restrict__ W,    // WkvT (2048, 256)
    ushort_t* __restrict__ O)          // (b*128+i, 1024)
{
    __shared__ ushort_t sKV[2][128 * 72];   // 36.9 KB kv sub-tiles (dbuf)
    __shared__ ushort_t sKc[128 * 72];      // 18.4 KB  Kc (j, d)
    __shared__ ushort_t sVt[64 * 136];      // 17.4 KB  Vc^T (d, j)
    __shared__ ushort_t sP[8 * 16 * 136];   // 34.8 KB  per-wave P buffers

    const int bh = blockIdx.x;
    const int b = bh >> 4, h = bh & 15;
    const int tid  = threadIdx.x;
    const int lane = tid & 63, w = tid >> 6;
    const int quad = lane >> 4, l15 = lane & 15;
    const int wr = w >> 2, wc = w & 3;      // proj mapping

    // ---- W-slice fragments in registers: wf[ks 0..7][nt 0..1] ----
    // col n = wc*32 + nt*16 + l15; n<64 -> K row h*64+n ; else V row 1024+h*64+(n-64)
    short8 wf[8][2];
#pragma unroll
    for (int nt = 0; nt < 2; nt++) {
        int n = wc * 32 + nt * 16 + l15;
        int grow = (n < 64) ? (h * 64 + n) : (1024 + h * 64 + (n - 64));
        const ushort_t* wp = &W[(size_t)grow * 256 + quad * 8];
#pragma unroll
        for (int ks = 0; ks < 8; ks++)
            wf[ks][nt] = *(const short8*)(wp + ks * 32);
    }

    // ---- Q fragments (attn i-tile = w) ----
    const ushort_t* qrow = &Q[(size_t)(b * 128 + w * 16 + l15) * 1024 + h * 64 + quad * 8];
    short8 aq0 = *(const short8*)qrow;
    short8 aq1 = *(const short8*)(qrow + 32);

    float mrow[4], lrow[4];
    floatx4 acc_o[4];
#pragma unroll
    for (int r = 0; r < 4; r++) { mrow[r] = -1e30f; lrow[r] = 0.f; }
#pragma unroll
    for (int dt = 0; dt < 4; dt++) acc_o[dt] = (floatx4){0.f, 0.f, 0.f, 0.f};

    ushort_t* sp = &sP[w * 2176];
    const int srow = tid >> 2;              // staging: 512 thr -> 128 rows x 4 chunks
    const int sc8  = tid & 3;

    for (int c4 = 0; c4 < 4; c4++) {
        const int j0 = c4 * 128;
        const ushort_t* kvbase = &KV[(size_t)(b * 512 + j0) * 256];

        // stage kv_sub k0=0 into buf0 (each thread: 2 x 16B)
#pragma unroll
        for (int t = 0; t < 2; t++) {
            int cc = tid + t * 512;
            int row = cc >> 3, c8 = cc & 7;
            *(short8*)&sKV[0][row * 72 + c8 * 8] =
                *(const short8*)&kvbase[(size_t)row * 256 + c8 * 8];
        }
        __syncthreads();                                   // B1

        floatx4 pacc[4][2];
#pragma unroll
        for (int i = 0; i < 4; i++)
#pragma unroll
            for (int nt = 0; nt < 2; nt++) pacc[i][nt] = (floatx4){0.f, 0.f, 0.f, 0.f};

        for (int kb = 0; kb < 4; kb++) {
            const int buf = kb & 1;
            if (kb < 3) {                                   // prefetch next sub-tile
                int k0n = (kb + 1) * 64;
#pragma unroll
                for (int t = 0; t < 2; t++) {
                    int cc = tid + t * 512;
                    int row = cc >> 3, c8 = cc & 7;
                    *(short8*)&sKV[buf ^ 1][row * 72 + c8 * 8] =
                        *(const short8*)&kvbase[(size_t)row * 256 + k0n + c8 * 8];
                }
            }
#pragma unroll
            for (int ks2 = 0; ks2 < 2; ks2++) {
                short8 af[4];
#pragma unroll
                for (int i = 0; i < 4; i++)
                    af[i] = *(const short8*)&sKV[buf][(wr * 64 + i * 16 + l15) * 72 + ks2 * 32 + quad * 8];
#pragma unroll
                for (int i = 0; i < 4; i++)
#pragma unroll
                    for (int nt = 0; nt < 2; nt++)
                        pacc[i][nt] = __builtin_amdgcn_mfma_f32_16x16x32_bf16(
                            af[i], wf[kb * 2 + ks2][nt], pacc[i][nt], 0, 0, 0);
            }
            __syncthreads();                                // B2..B5
        }

        // ---- write Kc / Vt^T to LDS (C layout: row j = quad*4+r, col = l15) --
        if (wc < 2) {
#pragma unroll
            for (int i = 0; i < 4; i++)
#pragma unroll
                for (int nt = 0; nt < 2; nt++) {
                    int d = wc * 32 + nt * 16 + l15;
                    int jb = wr * 64 + i * 16 + quad * 4;
#pragma unroll
                    for (int r = 0; r < 4; r++)
                        sKc[(jb + r) * 72 + d] = f2bf(pacc[i][nt][r]);
                }
        } else {
#pragma unroll
            for (int i = 0; i < 4; i++)
#pragma unroll
                for (int nt = 0; nt < 2; nt++) {
                    int d = (wc - 2) * 32 + nt * 16 + l15;
                    int jb = wr * 64 + i * 16 + quad * 4;
                    ushortv4 p;
#pragma unroll
                    for (int r = 0; r < 4; r++) p[r] = f2bf(pacc[i][nt][r]);
                    *(ushortv4*)&sVt[d * 136 + jb] = p;
                }
        }
        __syncthreads();                                    // B6

        // ---- S = Q * Kc^T (16 x 128) in registers ----
        floatx4 s[8];
#pragma unroll
        for (int jt = 0; jt < 8; jt++) {
            const ushort_t* kp = &sKc[(jt * 16 + l15) * 72 + quad * 8];
            short8 bk0 = *(const short8*)kp;
            short8 bk1 = *(const short8*)(kp + 32);
            floatx4 a = (floatx4){0.f, 0.f, 0.f, 0.f};
            a = __builtin_amdgcn_mfma_f32_16x16x32_bf16(aq0, bk0, a, 0, 0, 0);
            a = __builtin_amdgcn_mfma_f32_16x16x32_bf16(aq1, bk1, a, 0, 0, 0);
            s[jt] = a;
        }

        // ---- online softmax ----
#pragma unroll
        for (int r = 0; r < 4; r++) {
            float mx = s[0][r];
#pragma unroll
            for (int jt = 1; jt < 8; jt++) mx = fmaxf(mx, s[jt][r]);
#pragma unroll
            for (int off = 1; off < 16; off <<= 1) mx = fmaxf(mx, __shfl_xor(mx, off));
            float mnew = fmaxf(mrow[r], mx);
            float alpha = __expf(mrow[r] - mnew);
            mrow[r] = mnew;
            float psum = 0.f;
#pragma unroll
            for (int jt = 0; jt < 8; jt++) {
                float p = __expf(s[jt][r] - mnew);
                s[jt][r] = p;
                psum += p;
            }
#pragma unroll
            for (int off = 1; off < 16; off <<= 1) psum += __shfl_xor(psum, off);
            lrow[r] = lrow[r] * alpha + psum;
#pragma unroll
            for (int dt = 0; dt < 4; dt++) acc_o[dt][r] *= alpha;
        }

        // ---- P -> per-wave LDS buffer (private, no barrier) ----
#pragma unroll
        for (int jt = 0; jt < 8; jt++)
#pragma unroll
            for (int r = 0; r < 4; r++)
                sp[(quad * 4 + r) * 136 + jt * 16 + l15] = f2bf(s[jt][r]);

        // ---- O += P * V ----
#pragma unroll
        for (int kk = 0; kk < 4; kk++) {
            short8 ap = *(const short8*)&sp[l15 * 136 + kk * 32 + quad * 8];
#pragma unroll
            for (int dt = 0; dt < 4; dt++) {
                short8 bv = *(const short8*)&sVt[(dt * 16 + l15) * 136 + kk * 32 + quad * 8];
                acc_o[dt] = __builtin_amdgcn_mfma_f32_16x16x32_bf16(ap, bv, acc_o[dt], 0, 0, 0);
            }
        }
        __syncthreads();                                    // B7: sVt/sKc reusable
    }

    // ---- epilogue: normalize and write (b*128+i, h*64+d) ----
#pragma unroll
    for (int r = 0; r < 4; r++) {
        float inv = 1.0f / lrow[r];
        size_t rowo = (size_t)(b * 128 + w * 16 + quad * 4 + r) * 1024 + h * 64;
#pragma unroll
        for (int dt = 0; dt < 4; dt++)
            O[rowo + dt * 16 + l15] = f2bf(acc_o[dt][r] * inv);
    }
}

// ---------------- launch ----------------
extern "C" void kernel_launch(void* const* d_in, const int* in_sizes, int n_in,
                              void* d_out, int out_size, void* d_ws, size_t ws_size,
                              hipStream_t stream) {
    const float* q   = (const float*)d_in[0];   // (64,128,512)
    const float* kv  = (const float*)d_in[1];   // (64,512,256)
    const float* Wq  = (const float*)d_in[2];   // (512,1024)
    const float* Wkv = (const float*)d_in[3];   // (256,2048)
    const float* Wo  = (const float*)d_in[4];   // (1024,512)
    const float* bo  = (const float*)d_in[5];   // (512,)
    float* out = (float*)d_out;

    char* ws = (char*)d_ws;
    ushort_t* qA    = (ushort_t*)(ws + 0);          //  8 MB  (8192 x 512)
    ushort_t* kvA   = (ushort_t*)(ws + 8388608);    // 16 MB  (32768 x 256)
    ushort_t* WqT   = (ushort_t*)(ws + 25165824);   //  1 MB  (1024 x 512)
    ushort_t* WkvT  = (ushort_t*)(ws + 26214400);   //  1 MB  (2048 x 256)
    ushort_t* WoT   = (ushort_t*)(ws + 27262976);   //  1 MB  (512 x 1024)
    ushort_t* qraw  = (ushort_t*)(ws + 28311552);   // 16 MB  (8192 x 1024)
    ushort_t* attnO = (ushort_t*)(ws + 45088768);   // 16 MB  (8192 x 1024)

    const float scale = 0.125f;  // HEAD_DIM^-0.5, folded into Wq

    hipLaunchKernelGGL(cast_bf16_kernel, dim3(4096), dim3(256), 0, stream, q,  qA,  4194304 / 4);
    hipLaunchKernelGGL(cast_bf16_kernel, dim3(8192), dim3(256), 0, stream, kv, kvA, 8388608 / 4);
    hipLaunchKernelGGL(tcast_kernel, dim3(2048), dim3(256), 0, stream, Wq,  WqT,  512,  1024, scale);
    hipLaunchKernelGGL(tcast_kernel, dim3(2048), dim3(256), 0, stream, Wkv, WkvT, 256,  2048, 1.0f);
    hipLaunchKernelGGL(tcast_kernel, dim3(2048), dim3(256), 0, stream, Wo,  WoT,  1024, 512,  1.0f);

    // qraw = (q @ Wq) * scale, row-major bf16   [gx=8, gy=64]
    hipLaunchKernelGGL(gemm_bt_kernel, dim3(512), dim3(256), 0, stream,
                       qA, WqT, 8192, 1024, 512, 8, 64, 0, qraw,
                       (float*)nullptr, (const float*)nullptr);
    // fused kv-projection + attention
    hipLaunchKernelGGL(fattn_kernel, dim3(1024), dim3(512), 0, stream,
                       qraw, kvA, WkvT, attnO);
    // out = attnO @ Wo + bo   [gx=4, gy=64]
    hipLaunchKernelGGL(gemm_bt_kernel, dim3(256), dim3(256), 0, stream,
                       attnO, WoT, 8192, 512, 1024, 4, 64, 2, (ushort_t*)nullptr,
                       out, bo);
}